// Round 5
// baseline (137.518 us; speedup 1.0000x reference)
//
#include <hip/hip_runtime.h>
#include <math.h>

#define BDIM 8
#define NDIM 128
#define TDIM 1024
#define TPB 512
#define EPT 8               // contiguous T-elements per thread (4 float4 = 64B)
#define CT 64               // T-elements per chunk
#define TPR (CT / EPT)      // 8 threads per row-chunk
#define RPI (TPB / TPR)     // 64 rows per iteration
#define NIT (NDIM / RPI)    // 2 iterations
#define SXN (CT + 2)        // std_x table: t = tc-1 .. tc+CT          (66)
#define SYN (NDIM + CT + 1) // std_y table: e = tc-1 .. tc+CT+NDIM-1   (193)

#define EPS_F 1e-12f
#define RHO_LIM_F (1.0f - 1e-6f)
#define PI_F 3.14159265358979323846f

// Fast path identity (exact for all p >= 0 incl. p < eps):
//   p * clamp(kgp / max(p,eps), -RHO, RHO) == clamp(kgp, -p*RHO, p*RHO)
// so when one_m == (1-a)^2 == 0:  c0 = hc * med3(kgp, -p*RHO, p*RHO), no rcp.
// Pad elements pass k = 0 AND std = 0 -> c0 = cn = 0 on both paths.
__device__ __forceinline__ void kfun(float kgp, float kntk, float sx, float sy,
                                     float one_m, float coef, bool fast,
                                     float& c0, float& cn)
{
    const float inv2pi = 0.15915494309189535f;
    const float p = sx * sy;   // std_x * std_y, as in reference
    if (fast) {
        const float hc = 0.5f * coef;
        const float pr = p * RHO_LIM_F;
        c0 = hc * fminf(fmaxf(kgp, -pr), pr);   // v_med3_f32
        cn = hc * kntk;
    } else {
        const float r  = fminf(fmaxf(kgp * __builtin_amdgcn_rcpf(fmaxf(p, EPS_F)), -RHO_LIM_F), RHO_LIM_F);
        const float th = acosf(r);
        const float s  = sqrtf(1.0f - r * r);
        const float br = coef * PI_F - one_m * th;
        c0 = p * inv2pi * (one_m * s + r * br);
        cn = br * inv2pi * kntk;
    }
}

__global__ __launch_bounds__(TPB) void conv_arccos_kernel(
    const float* __restrict__ k,      // (B,B,N,T,2)
    const float* __restrict__ leak,   // scalar
    const float* __restrict__ alpha,  // (3,)
    const float* __restrict__ beta,   // scalar
    float* __restrict__ out)          // (B,B,N,T,2)
{
    __shared__ float sx_lds[SXN];     // std_x at t = tc-1+j
    __shared__ float sy_lds[SYN];     // std_y at e = tc-1+j (0 past T: v_pad)

    const int chunk = blockIdx.x & 15;        // T-chunk index
    const int bb    = blockIdx.x >> 4;        // b1*8 + b2
    const int b2    = bb & (BDIM - 1);
    const int b1    = bb >> 3;
    const int tc    = chunk * CT;

    const int tid  = threadIdx.x;
    const int r_t  = tid & (TPR - 1);         // 0..7: tile within row-chunk
    const int rsel = tid >> 3;                // 0..63: row within iteration

    // forward value of clamp_pg(x) is max(x, 0)
    const float a   = fmaxf(leak[0], 0.0f);
    const float w0  = fmaxf(alpha[0], 0.0f);
    const float w1  = fmaxf(alpha[1], 0.0f);
    const float w2  = fmaxf(alpha[2], 0.0f);
    const float bia = fmaxf(beta[0], 0.0f);

    const float one_m = (1.0f - a) * (1.0f - a);
    const float coef  = 1.0f + a * a;
    const bool  fast  = (one_m == 0.0f);

    // v[b,t] = k[b,b,0,t,0]
    const float2* vrx = (const float2*)k + (size_t)(b1 * BDIM + b1) * NDIM * TDIM;
    const float2* vry = (const float2*)k + (size_t)(b2 * BDIM + b2) * NDIM * TDIM;

    // ---- once per block: std tables (all sqrt / v-loads leave the hot loop) ----
    if (tid < SXN) {
        const int t = tc - 1 + tid;
        const float v = (t >= 0 && t < TDIM) ? vrx[t].x : 0.0f;
        sx_lds[tid] = sqrtf(fmaxf(v, 0.0f));
    } else if (tid < SXN + SYN) {
        const int j = tid - SXN;
        const int e = tc - 1 + j;
        const float v = (e >= 0 && e < TDIM) ? vry[e].x : 0.0f;
        sy_lds[j] = sqrtf(fmaxf(v, 0.0f));
    }
    __syncthreads();   // the only barrier

    // per-thread invariants: std_x at t0-1 .. t0+8 (block-invariant -> registers)
    float sxv[EPT + 2];
    #pragma unroll
    for (int j = 0; j < EPT + 2; ++j) sxv[j] = sx_lds[EPT * r_t + j];

    const int  t0     = tc + EPT * r_t;
    const bool lvalid = (t0 > 0);             // left conv-pad only at t=0
    const bool rvalid = (t0 + EPT < TDIM);    // right conv-pad only at t=1023
    const int  eli    = max(t0 - 1, 0);
    const int  eri    = min(t0 + EPT, TDIM - 1);
    const int  fbase  = t0 >> 1;              // float4 index within row

    #pragma unroll
    for (int i = 0; i < NIT; ++i) {
        const int n   = i * RPI + rsel;
        const int row = bb * NDIM + n;
        const float* krow = k + (size_t)row * (TDIM * 2);

        // 64B contiguous per thread (4x dwordx4), halos L1-hot
        const float4* k4 = (const float4*)krow + fbase;
        const float4 kv0 = k4[0];
        const float4 kv1 = k4[1];
        const float4 kv2 = k4[2];
        const float4 kv3 = k4[3];
        const float2 kl  = ((const float2*)krow)[eli];
        const float2 kr  = ((const float2*)krow)[eri];

        // std_y at e = n+t0-1 .. n+t0+8 (10 consecutive LDS floats)
        float syv[EPT + 2];
        #pragma unroll
        for (int j = 0; j < EPT + 2; ++j) syv[j] = sy_lds[n + EPT * r_t + j];

        // c values for elements t0-1 .. t0+8 (index shifted by +1)
        float c0[EPT + 2], cn[EPT + 2];
        kfun(lvalid ? kl.x : 0.0f, lvalid ? kl.y : 0.0f, sxv[0], syv[0], one_m, coef, fast, c0[0], cn[0]);
        kfun(kv0.x, kv0.y, sxv[1], syv[1], one_m, coef, fast, c0[1], cn[1]);
        kfun(kv0.z, kv0.w, sxv[2], syv[2], one_m, coef, fast, c0[2], cn[2]);
        kfun(kv1.x, kv1.y, sxv[3], syv[3], one_m, coef, fast, c0[3], cn[3]);
        kfun(kv1.z, kv1.w, sxv[4], syv[4], one_m, coef, fast, c0[4], cn[4]);
        kfun(kv2.x, kv2.y, sxv[5], syv[5], one_m, coef, fast, c0[5], cn[5]);
        kfun(kv2.z, kv2.w, sxv[6], syv[6], one_m, coef, fast, c0[6], cn[6]);
        kfun(kv3.x, kv3.y, sxv[7], syv[7], one_m, coef, fast, c0[7], cn[7]);
        kfun(kv3.z, kv3.w, sxv[8], syv[8], one_m, coef, fast, c0[8], cn[8]);
        kfun(rvalid ? kr.x : 0.0f, rvalid ? kr.y : 0.0f, sxv[9], syv[9], one_m, coef, fast, c0[9], cn[9]);

        // kg[t] = w0*c0[t-1]+w1*c0[t]+w2*c0[t+1]+bia ; kn = conv(cn)+kg
        float4 o[EPT / 2];
        #pragma unroll
        for (int d = 0; d < EPT; d += 2) {
            const float kg0 = fmaf(w0, c0[d],     fmaf(w1, c0[d + 1], fmaf(w2, c0[d + 2], bia)));
            const float kg1 = fmaf(w0, c0[d + 1], fmaf(w1, c0[d + 2], fmaf(w2, c0[d + 3], bia)));
            const float kn0 = fmaf(w0, cn[d],     fmaf(w1, cn[d + 1], fmaf(w2, cn[d + 2], kg0)));
            const float kn1 = fmaf(w0, cn[d + 1], fmaf(w1, cn[d + 2], fmaf(w2, cn[d + 3], kg1)));
            o[d >> 1] = make_float4(kg0, kn0, kg1, kn1);
        }

        float4* o4 = (float4*)(out + (size_t)row * (TDIM * 2)) + fbase;
        o4[0] = o[0];
        o4[1] = o[1];
        o4[2] = o[2];
        o4[3] = o[3];
    }
}

extern "C" void kernel_launch(void* const* d_in, const int* in_sizes, int n_in,
                              void* d_out, int out_size, void* d_ws, size_t ws_size,
                              hipStream_t stream) {
    const float* k     = (const float*)d_in[0];
    const float* leak  = (const float*)d_in[1];
    const float* alpha = (const float*)d_in[2];
    const float* beta  = (const float*)d_in[3];
    float* out = (float*)d_out;

    const int n_blocks = BDIM * BDIM * (TDIM / CT);   // 1024
    conv_arccos_kernel<<<n_blocks, TPB, 0, stream>>>(k, leak, alpha, beta, out);
}

// Round 7
// 122.094 us; speedup vs baseline: 1.1263x; 1.1263x over previous
//
#include <hip/hip_runtime.h>
#include <math.h>

#define BDIM 8
#define NDIM 128
#define TDIM 1024
#define TPB 1024
#define CT 128              // T-elements per chunk; ONE WAVE owns one row-chunk
#define NCHUNK (TDIM / CT)  // 8
#define WPB (TPB / 64)      // 16 waves per block
#define NIT (NDIM / WPB)    // 8 row-iterations per wave
#define SXN (CT + 2)        // 130: std_x at t = tc-1 .. tc+CT
#define SYN (NDIM + CT + 1) // 257: std_y at e = tc-1 .. tc+CT+NDIM-1

#define EPS_F 1e-12f
#define RHO_LIM_F (1.0f - 1e-6f)
#define PI_F 3.14159265358979323846f

// Fast path identity (exact for all p >= 0 incl. p < eps):
//   p * clamp(kgp / max(p,eps), -RHO, RHO) == clamp(kgp, -p*RHO, p*RHO)
// so when one_m == (1-a)^2 == 0:  c0 = hc * med3(kgp, -p*RHO, p*RHO), no rcp.
// Pad elements pass k = 0 AND std = 0 -> c0 = cn = 0 on both paths.
__device__ __forceinline__ void kfun(float kgp, float kntk, float sx, float sy,
                                     float one_m, float coef, bool fast,
                                     float& c0, float& cn)
{
    const float inv2pi = 0.15915494309189535f;
    const float p = sx * sy;   // std_x * std_y, as in reference
    if (fast) {
        const float hc = 0.5f * coef;
        const float pr = p * RHO_LIM_F;
        c0 = hc * fminf(fmaxf(kgp, -pr), pr);   // v_med3_f32
        cn = hc * kntk;
    } else {
        const float r  = fminf(fmaxf(kgp * __builtin_amdgcn_rcpf(fmaxf(p, EPS_F)), -RHO_LIM_F), RHO_LIM_F);
        const float th = acosf(r);
        const float s  = sqrtf(1.0f - r * r);
        const float br = coef * PI_F - one_m * th;
        c0 = p * inv2pi * (one_m * s + r * br);
        cn = br * inv2pi * kntk;
    }
}

__global__ __launch_bounds__(TPB) void conv_arccos_kernel(
    const float* __restrict__ k,      // (B,B,N,T,2)
    const float* __restrict__ leak,   // scalar
    const float* __restrict__ alpha,  // (3,)
    const float* __restrict__ beta,   // scalar
    float* __restrict__ out)          // (B,B,N,T,2)
{
    __shared__ float sx_lds[SXN];     // std_x at t = tc-1+j
    __shared__ float sy_lds[SYN];     // std_y at e = tc-1+j (0 past T: v_pad)

    const int chunk = blockIdx.x & (NCHUNK - 1);
    const int bb    = blockIdx.x >> 3;        // b1*8 + b2
    const int b2    = bb & (BDIM - 1);
    const int b1    = bb >> 3;
    const int tc    = chunk * CT;

    const int tid  = threadIdx.x;
    const int lane = tid & 63;
    const int wid  = tid >> 6;

    // forward value of clamp_pg(x) is max(x, 0)
    const float a   = fmaxf(leak[0], 0.0f);
    const float w0  = fmaxf(alpha[0], 0.0f);
    const float w1  = fmaxf(alpha[1], 0.0f);
    const float w2  = fmaxf(alpha[2], 0.0f);
    const float bia = fmaxf(beta[0], 0.0f);

    const float one_m = (1.0f - a) * (1.0f - a);
    const float coef  = 1.0f + a * a;
    const bool  fast  = (one_m == 0.0f);

    // v[b,t] = k[b,b,0,t,0]
    const float2* vrx = (const float2*)k + (size_t)(b1 * BDIM + b1) * NDIM * TDIM;
    const float2* vry = (const float2*)k + (size_t)(b2 * BDIM + b2) * NDIM * TDIM;

    // ---- once per block: std tables (all sqrt / v-loads / pad masks leave hot loop) ----
    if (tid < SXN) {
        const int t = tc - 1 + tid;
        const float v = (t >= 0 && t < TDIM) ? vrx[t].x : 0.0f;
        sx_lds[tid] = sqrtf(fmaxf(v, 0.0f));
    } else if (tid < SXN + SYN) {
        const int j = tid - SXN;
        const int e = tc - 1 + j;
        const float v = (e >= 0 && e < TDIM) ? vry[e].x : 0.0f;
        sy_lds[j] = sqrtf(fmaxf(v, 0.0f));
    }
    __syncthreads();   // the only barrier

    // per-lane invariants (block-invariant -> registers)
    const float sx0 = sx_lds[2 * lane + 1];   // std_x(t0)
    const float sx1 = sx_lds[2 * lane + 2];   // std_x(t0+1)
    const float sxm = sx_lds[0];              // std_x(tc-1), edge lanes only
    const float sxp = sx_lds[CT + 1];         // std_x(tc+CT), edge lanes only

    const bool lhalo = (lane == 0)  && (tc > 0);         // chunk 0: conv left pad = 0
    const bool rhalo = (lane == 63) && (tc + CT < TDIM); // last chunk: right pad = 0
    const int  g     = (tc >> 1) + lane;      // float4 index within row (coalesced)

    #pragma unroll 2
    for (int i = 0; i < NIT; ++i) {
        const int n   = i * WPB + wid;
        const int row = bb * NDIM + n;
        const float* krow = k + (size_t)row * (TDIM * 2);

        // the ONLY per-pair vmem ops: one 16B load, one 16B store
        const float4 kv = ((const float4*)krow)[g];
        const float sy0 = sy_lds[n + 2 * lane + 1];   // ds_read2_b32
        const float sy1 = sy_lds[n + 2 * lane + 2];

        float c00, cn0, c01, cn1;
        kfun(kv.x, kv.y, sx0, sy0, one_m, coef, fast, c00, cn0);
        kfun(kv.z, kv.w, sx1, sy1, one_m, coef, fast, c01, cn1);

        // chunk-edge halo c-values: computed only on edge lanes, 8B L1-hot loads
        float c0lh = 0.0f, cnlh = 0.0f, c0rh = 0.0f, cnrh = 0.0f;
        if (lhalo) {
            const float2 kl = ((const float2*)krow)[tc - 1];
            kfun(kl.x, kl.y, sxm, sy_lds[n], one_m, coef, fast, c0lh, cnlh);
        }
        if (rhalo) {
            const float2 kr = ((const float2*)krow)[tc + CT];
            kfun(kr.x, kr.y, sxp, sy_lds[n + CT + 1], one_m, coef, fast, c0rh, cnrh);
        }

        // interior halos from neighbor lanes (DS pipe, no vmem)
        float c0l = __shfl_up(c01, 1);
        float cnl = __shfl_up(cn1, 1);
        float c0r = __shfl_down(c00, 1);
        float cnr = __shfl_down(cn0, 1);
        if (lane == 0)  { c0l = c0lh; cnl = cnlh; }
        if (lane == 63) { c0r = c0rh; cnr = cnrh; }

        // kg = conv(c0) + bia ; kn = conv(cn) + kg
        const float kg0 = fmaf(w0, c0l, fmaf(w1, c00, fmaf(w2, c01, bia)));
        const float kg1 = fmaf(w0, c00, fmaf(w1, c01, fmaf(w2, c0r, bia)));
        const float kn0 = fmaf(w0, cnl, fmaf(w1, cn0, fmaf(w2, cn1, kg0)));
        const float kn1 = fmaf(w0, cn0, fmaf(w1, cn1, fmaf(w2, cnr, kg1)));

        ((float4*)(out + (size_t)row * (TDIM * 2)))[g] = make_float4(kg0, kn0, kg1, kn1);
    }
}

extern "C" void kernel_launch(void* const* d_in, const int* in_sizes, int n_in,
                              void* d_out, int out_size, void* d_ws, size_t ws_size,
                              hipStream_t stream) {
    const float* k     = (const float*)d_in[0];
    const float* leak  = (const float*)d_in[1];
    const float* alpha = (const float*)d_in[2];
    const float* beta  = (const float*)d_in[3];
    float* out = (float*)d_out;

    const int n_blocks = BDIM * BDIM * NCHUNK;   // 512; 2 blocks/CU, 32 waves/CU
    conv_arccos_kernel<<<n_blocks, TPB, 0, stream>>>(k, leak, alpha, beta, out);
}

// Round 8
// 120.054 us; speedup vs baseline: 1.1455x; 1.0170x over previous
//
#include <hip/hip_runtime.h>
#include <math.h>

#define BDIM 8
#define NDIM 128
#define TDIM 1024
#define TPB 512
#define CT 128               // T-elements per wave-chunk (one wave owns 128 elems of a row)
#define NCHUNK (TDIM / CT)   // 8
#define WPB (TPB / 64)       // 8 waves per block
#define NIT 8                // rows per wave, ALL loads hoisted (MLP depth 8)
#define RPB (WPB * NIT)      // 64 rows per block
#define NHALF (NDIM / RPB)   // 2
#define SXN (CT + 2)         // 130: std_x at t = tc-1 .. tc+CT
#define SYN (RPB + CT + 1)   // 193: std_y at e = nbase+tc-1 .. nbase+tc+191

#define EPS_F 1e-12f
#define RHO_LIM_F (1.0f - 1e-6f)
#define PI_F 3.14159265358979323846f

// Fast path identity (exact for all p >= 0 incl. p < eps):
//   p * clamp(kgp / max(p,eps), -RHO, RHO) == clamp(kgp, -p*RHO, p*RHO)
// so when one_m == (1-a)^2 == 0:  c0 = hc * med3(kgp, -p*RHO, p*RHO), no rcp.
// Pad elements MUST pass sx = 0 (not just k = 0): slow path's c0 has a
// p*one_m*s term that is nonzero unless p = 0.
__device__ __forceinline__ void kfun(float kgp, float kntk, float sx, float sy,
                                     float one_m, float coef, bool fast,
                                     float& c0, float& cn)
{
    const float inv2pi = 0.15915494309189535f;
    const float p = sx * sy;   // std_x * std_y, as in reference
    if (fast) {
        const float hc = 0.5f * coef;
        const float pr = p * RHO_LIM_F;
        c0 = hc * fminf(fmaxf(kgp, -pr), pr);   // v_med3_f32
        cn = hc * kntk;
    } else {
        const float r  = fminf(fmaxf(kgp * __builtin_amdgcn_rcpf(fmaxf(p, EPS_F)), -RHO_LIM_F), RHO_LIM_F);
        const float th = acosf(r);
        const float s  = sqrtf(1.0f - r * r);
        const float br = coef * PI_F - one_m * th;
        c0 = p * inv2pi * (one_m * s + r * br);
        cn = br * inv2pi * kntk;
    }
}

__global__ __launch_bounds__(TPB, 4) void conv_arccos_kernel(
    const float* __restrict__ k,      // (B,B,N,T,2)
    const float* __restrict__ leak,   // scalar
    const float* __restrict__ alpha,  // (3,)
    const float* __restrict__ beta,   // scalar
    float* __restrict__ out)          // (B,B,N,T,2)
{
    __shared__ float sx_lds[SXN];     // std_x at t = tc-1+j
    __shared__ float sy_lds[SYN];     // std_y at e = nbase+tc-1+j (0 past T)

    const int chunk = blockIdx.x & (NCHUNK - 1);
    const int nh    = (blockIdx.x >> 3) & (NHALF - 1);
    const int bb    = blockIdx.x >> 4;        // b1*8 + b2
    const int b2    = bb & (BDIM - 1);
    const int b1    = bb >> 3;
    const int tc    = chunk * CT;
    const int nbase = nh * RPB;

    const int tid  = threadIdx.x;
    const int lane = tid & 63;
    const int wid  = tid >> 6;

    // forward value of clamp_pg(x) is max(x, 0)
    const float a   = fmaxf(leak[0], 0.0f);
    const float w0  = fmaxf(alpha[0], 0.0f);
    const float w1  = fmaxf(alpha[1], 0.0f);
    const float w2  = fmaxf(alpha[2], 0.0f);
    const float bia = fmaxf(beta[0], 0.0f);

    const float one_m = (1.0f - a) * (1.0f - a);
    const float coef  = 1.0f + a * a;
    const bool  fast  = (one_m == 0.0f);

    // v[b,t] = k[b,b,0,t,0]
    const float2* vrx = (const float2*)k + (size_t)(b1 * BDIM + b1) * NDIM * TDIM;
    const float2* vry = (const float2*)k + (size_t)(b2 * BDIM + b2) * NDIM * TDIM;

    // ---- once per block: std tables (sqrt / v-loads / pad masks leave hot path) ----
    if (tid < SXN) {
        const int t = tc - 1 + tid;
        const float v = (t >= 0 && t < TDIM) ? vrx[t].x : 0.0f;
        sx_lds[tid] = sqrtf(fmaxf(v, 0.0f));
    } else if (tid < SXN + SYN) {
        const int j = tid - SXN;
        const int e = nbase + tc - 1 + j;
        const float v = (e >= 0 && e < TDIM) ? vry[e].x : 0.0f;
        sy_lds[j] = sqrtf(fmaxf(v, 0.0f));
    }
    __syncthreads();   // the only barrier

    // per-lane invariants
    const float sx0 = sx_lds[2 * lane + 1];   // std_x(t0)
    const float sx1 = sx_lds[2 * lane + 2];   // std_x(t0+1)
    // edge-halo role: lane 0 -> left halo (tc-1), lane 63 -> right halo (tc+CT)
    const bool hval = (lane == 0) ? (tc > 0)
                    : ((lane == 63) ? (tc + CT < TDIM) : false);
    const float sxh = hval ? ((lane == 0) ? sx_lds[0] : sx_lds[CT + 1]) : 0.0f;
    const int   eh  = (lane == 0) ? (tc - 1) : (tc + CT);   // float2 index in row
    const int   jh  = (lane == 63) ? (CT + 1) : 0;          // syh table offset
    const int   g   = (tc >> 1) + lane;                     // float4 index in row

    const size_t rowstride = (size_t)TDIM * 2;
    const float* krow0 = k   + ((size_t)(bb * NDIM + nbase)) * rowstride;
    float*       orow0 = out + ((size_t)(bb * NDIM + nbase)) * rowstride;

    // ---- hoist ALL loads: 8 independent 16B global loads in flight per wave ----
    float4 kv[NIT];
    #pragma unroll
    for (int i = 0; i < NIT; ++i) {
        const float* kr = krow0 + (size_t)(i * WPB + wid) * rowstride;
        kv[i] = ((const float4*)kr)[g];
    }
    float khg[NIT], khn[NIT];
    #pragma unroll
    for (int i = 0; i < NIT; ++i) {
        khg[i] = 0.0f; khn[i] = 0.0f;
        if (hval) {
            const float2 h = ((const float2*)(krow0 + (size_t)(i * WPB + wid) * rowstride))[eh];
            khg[i] = h.x; khn[i] = h.y;
        }
    }
    float sy0[NIT], sy1[NIT], syh[NIT];
    #pragma unroll
    for (int i = 0; i < NIT; ++i) {
        const int nl = i * WPB + wid;
        sy0[i] = sy_lds[nl + 2 * lane + 1];
        sy1[i] = sy_lds[nl + 2 * lane + 2];
        syh[i] = sy_lds[nl + jh];
    }

    // ---- compute + store: no global loads on this path ----
    #pragma unroll
    for (int i = 0; i < NIT; ++i) {
        float c00, cn0, c01, cn1, c0h, cnh;
        kfun(kv[i].x, kv[i].y, sx0, sy0[i], one_m, coef, fast, c00, cn0);
        kfun(kv[i].z, kv[i].w, sx1, sy1[i], one_m, coef, fast, c01, cn1);
        kfun(khg[i],  khn[i],  sxh, syh[i], one_m, coef, fast, c0h, cnh);  // sxh=0 when invalid -> 0

        // interior halos from neighbor lanes (DS pipe); edges from c0h/cnh
        float c0l = __shfl_up(c01, 1);
        float cnl = __shfl_up(cn1, 1);
        float c0r = __shfl_down(c00, 1);
        float cnr = __shfl_down(cn0, 1);
        if (lane == 0)  { c0l = c0h; cnl = cnh; }
        if (lane == 63) { c0r = c0h; cnr = cnh; }

        // kg = conv(c0) + bia ; kn = conv(cn) + kg
        const float kg0 = fmaf(w0, c0l, fmaf(w1, c00, fmaf(w2, c01, bia)));
        const float kg1 = fmaf(w0, c00, fmaf(w1, c01, fmaf(w2, c0r, bia)));
        const float kn0 = fmaf(w0, cnl, fmaf(w1, cn0, fmaf(w2, cn1, kg0)));
        const float kn1 = fmaf(w0, cn0, fmaf(w1, cn1, fmaf(w2, cnr, kg1)));

        ((float4*)(orow0 + (size_t)(i * WPB + wid) * rowstride))[g] =
            make_float4(kg0, kn0, kg1, kn1);
    }
}

extern "C" void kernel_launch(void* const* d_in, const int* in_sizes, int n_in,
                              void* d_out, int out_size, void* d_ws, size_t ws_size,
                              hipStream_t stream) {
    const float* k     = (const float*)d_in[0];
    const float* leak  = (const float*)d_in[1];
    const float* alpha = (const float*)d_in[2];
    const float* beta  = (const float*)d_in[3];
    float* out = (float*)d_out;

    const int n_blocks = BDIM * BDIM * NHALF * NCHUNK;   // 1024
    conv_arccos_kernel<<<n_blocks, TPB, 0, stream>>>(k, leak, alpha, beta, out);
}

// Round 9
// 118.638 us; speedup vs baseline: 1.1591x; 1.0119x over previous
//
#include <hip/hip_runtime.h>
#include <math.h>

#define BDIM 8
#define NDIM 128
#define TDIM 1024
#define TPB 512    // one float4 (elements t,t+1) per thread per row
#define ROWS 4     // rows per block; N=128 divisible by 4 -> same (b1,b2) per block
#define LSTRIDE 1028  // per-row LDS stride: idx0 = left halo (t=-1), t at idx t+1, right halo idx TDIM+1

#define EPS_F 1e-12f
#define RHO_LIM_F (1.0f - 1e-6f)
#define PI_F 3.14159265358979323846f

// Fast path identity (exact for all p >= 0 incl. p < eps):
//   p * clamp(kgp / max(p,eps), -RHO, RHO) == clamp(kgp, -p*RHO, p*RHO)
// so when one_m == (1-a)^2 == 0:  c0 = hc * med3(kgp, -p*RHO, p*RHO), no rcp.

__device__ __forceinline__ void kfun(float kgp, float kntk, float vx, float vy,
                                     float one_m, float coef, bool fast,
                                     float& c0, float& cn)
{
    const float inv2pi = 0.15915494309189535f;
    const float p = sqrtf(fmaxf(vx, 0.0f) * fmaxf(vy, 0.0f));
    if (fast) {
        const float hc = 0.5f * coef;
        const float pr = p * RHO_LIM_F;
        c0 = hc * fminf(fmaxf(kgp, -pr), pr);   // v_med3_f32
        cn = hc * kntk;
    } else {
        const float r  = fminf(fmaxf(kgp * __builtin_amdgcn_rcpf(fmaxf(p, EPS_F)), -RHO_LIM_F), RHO_LIM_F);
        const float th = acosf(r);
        const float s  = sqrtf(1.0f - r * r);
        const float br = coef * PI_F - one_m * th;
        c0 = p * inv2pi * (one_m * s + r * br);
        cn = br * inv2pi * kntk;
    }
}

__global__ __launch_bounds__(TPB) void conv_arccos_kernel(
    const float* __restrict__ k,      // (B,B,N,T,2)
    const float* __restrict__ leak,   // scalar
    const float* __restrict__ alpha,  // (3,)
    const float* __restrict__ beta,   // scalar
    float* __restrict__ out)          // (B,B,N,T,2)
{
    __shared__ float sc0[ROWS * LSTRIDE];
    __shared__ float scn[ROWS * LSTRIDE];

    const int base = blockIdx.x * ROWS;   // first row of this block
    const int n0   = base % NDIM;         // n of first row (multiple of 4)
    const int bb   = base / NDIM;
    const int b2   = bb % BDIM;
    const int b1   = bb / BDIM;
    const int tid  = threadIdx.x;
    const int t    = tid * 2;

    // forward value of clamp_pg(x) is max(x, 0)
    const float a   = fmaxf(leak[0], 0.0f);
    const float w0  = fmaxf(alpha[0], 0.0f);
    const float w1  = fmaxf(alpha[1], 0.0f);
    const float w2  = fmaxf(alpha[2], 0.0f);
    const float bia = fmaxf(beta[0], 0.0f);

    const float one_m = (1.0f - a) * (1.0f - a);
    const float coef  = 1.0f + a * a;
    const bool  fast  = (one_m == 0.0f);

    // v[b, t] = k[b, b, 0, t, 0]
    const float2* vrx = (const float2*)(k) + (size_t)(b1 * BDIM + b1) * NDIM * TDIM;
    const float2* vry = (const float2*)(k) + (size_t)(b2 * BDIM + b2) * NDIM * TDIM;

    // zero halos (left idx 0, right idx TDIM+1, per row)
    if (tid < ROWS * 2) {
        const int r   = tid >> 1;
        const int idx = r * LSTRIDE + ((tid & 1) ? (TDIM + 1) : 0);
        sc0[idx] = 0.0f;
        scn[idx] = 0.0f;
    }

    // ---- gather shared inputs ----
    // vx[t], vx[t+1] shared by all 4 rows (16B coalesced)
    const float4 vx2 = ((const float4*)vrx)[tid];
    // vy values y_j = v[b2, n0+t+j], j=0..4 cover row rl elem i at j=rl+i.
    // (n0+t) is even -> 16B-aligned float4 loads over the float2 array; lanes
    // stride 16B -> fully coalesced. Reads past row 0 of the (b2,b2) slice are
    // in-bounds garbage, masked below.
    const float4* vyp = (const float4*)(vry + (n0 + t));
    const float4 vyA = vyp[0];            // .x = y0, .z = y1
    const float4 vyB = vyp[1];            // .x = y2, .z = y3
    float y0 = vyA.x, y1 = vyA.z, y2 = vyB.x, y3 = vyB.z;
    float y4 = vry[n0 + t + 4].x;         // L1-hot (neighbors' vyA/vyB lines)
    const int ty = n0 + t;
    if (ty     >= TDIM) y0 = 0.0f;
    if (ty + 1 >= TDIM) y1 = 0.0f;
    if (ty + 2 >= TDIM) y2 = 0.0f;
    if (ty + 3 >= TDIM) y3 = 0.0f;
    if (ty + 4 >= TDIM) y4 = 0.0f;
    const float yv[6] = { y0, y1, y2, y3, y4, 0.0f };

    // ---- phase 1: 4 rows, one float4 of k each ----
    #pragma unroll
    for (int rl = 0; rl < ROWS; ++rl) {
        const float4 kv = ((const float4*)(k + (size_t)(base + rl) * TDIM * 2))[tid];
        float c00, cn0, c01, cn1;
        kfun(kv.x, kv.y, vx2.x, yv[rl],     one_m, coef, fast, c00, cn0);
        kfun(kv.z, kv.w, vx2.z, yv[rl + 1], one_m, coef, fast, c01, cn1);
        const int bi = rl * LSTRIDE + t + 1;
        sc0[bi]     = c00;
        sc0[bi + 1] = c01;
        scn[bi]     = cn0;
        scn[bi + 1] = cn1;
    }

    __syncthreads();

    // ---- phase 2: 3-tap conv per row, bias folded into FMA seed ----
    #pragma unroll
    for (int rl = 0; rl < ROWS; ++rl) {
        const int bi = rl * LSTRIDE + t;
        const float c0l = sc0[bi], c00 = sc0[bi + 1], c01 = sc0[bi + 2], c0r = sc0[bi + 3];
        const float cnl = scn[bi], cn0 = scn[bi + 1], cn1 = scn[bi + 2], cnr = scn[bi + 3];

        // kg = conv(c0) + bia ; kn = conv(cn) + kg   (kn = conv(cn)+conv(c0)+bia)
        const float kg0 = fmaf(w0, c0l, fmaf(w1, c00, fmaf(w2, c01, bia)));
        const float kg1 = fmaf(w0, c00, fmaf(w1, c01, fmaf(w2, c0r, bia)));
        const float kn0 = fmaf(w0, cnl, fmaf(w1, cn0, fmaf(w2, cn1, kg0)));
        const float kn1 = fmaf(w0, cn0, fmaf(w1, cn1, fmaf(w2, cnr, kg1)));

        float4 o;
        o.x = kg0; o.y = kn0; o.z = kg1; o.w = kn1;
        ((float4*)(out + (size_t)(base + rl) * TDIM * 2))[tid] = o;
    }
}

extern "C" void kernel_launch(void* const* d_in, const int* in_sizes, int n_in,
                              void* d_out, int out_size, void* d_ws, size_t ws_size,
                              hipStream_t stream) {
    const float* k     = (const float*)d_in[0];
    const float* leak  = (const float*)d_in[1];
    const float* alpha = (const float*)d_in[2];
    const float* beta  = (const float*)d_in[3];
    float* out = (float*)d_out;

    const int n_blocks = BDIM * BDIM * NDIM / ROWS;   // 2048
    conv_arccos_kernel<<<n_blocks, TPB, 0, stream>>>(k, leak, alpha, beta, out);
}